// Round 13
// baseline (178.093 us; speedup 1.0000x reference)
//
#include <hip/hip_runtime.h>
#include <math.h>

#define NB 4
#define C_IN 256
#define CKC 64
#define HWSZ 4096   // 64*64
#define K2 25

typedef float f32x2 __attribute__((ext_vector_type(2)));

// workspace layout (float offsets). cx region (1M floats) is dead post-fusion;
// wcT and the pk-friendly wT2 live there.
#define WS_WCT   0                               // 16384 floats
#define WS_WT2   16384                           // 27648 floats [c][tap][g][6]
#define WS_OFF   (NB*CKC*HWSZ)                   // 1048576
#define WS_MASK  (WS_OFF + NB*8*HWSZ)            // +131072

#define NWT2 (CKC * 9 * 8 * 6)   // 27648
#define NWC  (C_IN * CKC)        // 16384

// ---------------- Kernel D (v2): weight prep ----------------
// wT2[c][tap][g][6]: per-group 5 conv weights + 1 pad -> every f32x2 load
// 8B-aligned (g*6 floats = 24B). oc = g*5+j; oc 0..7 = offset conv,
// 8..32 = kernel conv, else pad. wcT[c][ck] for the compressor.
__global__ void k_wt(const float* __restrict__ wk, const float* __restrict__ wo,
                     const float* __restrict__ wc,
                     float* __restrict__ wT2, float* __restrict__ wcT) {
  int i = blockIdx.x * 256 + threadIdx.x;
  if (i < NWT2) {
    int j = i % 6;
    int r = i / 6;           // r = (c*9+tap)*8 + g
    int g = r % 8;
    int ct = r / 8;
    int tap = ct % 9, c = ct / 9;
    float v = 0.f;
    if (j < 5) {
      int oc = g * 5 + j;
      if (oc < 8)       v = wo[(oc * CKC + c) * 9 + tap];
      else if (oc < 33) v = wk[((oc - 8) * CKC + c) * 9 + tap];
    }
    wT2[i] = v;
  } else {
    int j = i - NWT2;
    if (j < NWC) {
      int c = j >> 6, ck = j & 63;
      wcT[j] = wc[ck * C_IN + c];
    }
  }
}

// ---------------- Kernel B (v9): FUSED compress+conv+softmax, 16 waves ----
// grid (64,4) x 1024 thr (4 waves/SIMD; v8 structure verified r12: 62->53us).
// v9: f32x2-packed FMA loops -> v_pk_fma_f32 (VOP3P: 2 fp32 FLOP per issue
// slot; m07: scalar fma = 103 TF vs 157 TF chip peak -- packed is the gap).
// Issue-floor arithmetic: v8 = 5536 scalar FMA/thread = 18.5us of pure
// issue at 4 waves/SIMD; v9 = 2912 slots = 9.7us.
//  - compress: acc pairs over ck (a0p/a1p[4]); weights as aligned f32x2
//    (g*8 floats = 32B); v0/v1 broadcast. 4096 -> 2048 slots.
//  - conv: wT2 layout gives 8B-aligned pairs; 2 pk + 1 scalar per tap.
//    1440 -> 864 slots. Per-output accumulation order unchanged vs v8.
__global__ __launch_bounds__(1024) void k_cs(const float* __restrict__ x,
    const float* __restrict__ wcT, const float* __restrict__ bc,
    const float* __restrict__ wT2, const float* __restrict__ bk, const float* __restrict__ bo,
    float* __restrict__ offb, float* __restrict__ maskb) {
  __attribute__((aligned(16))) __shared__ float s_mem[15360];  // 61440B union
  // compress: s_A = s_mem[0..7679], s_B = s_mem[7680..15359]  (64c x 120)
  // conv:     s_tile[64][144] = s_mem[0..9215]
  // epilogue: s_res[40*64]    = s_mem[0..2559]
  float* s_tile = s_mem;
  float* s_res  = s_mem;

  int t = threadIdx.x;
  int n = blockIdx.y;
  int tile = blockIdx.x;
  int x0 = (tile & 3) * 16, y0 = (tile >> 2) * 4;
  const float* xn = x + (size_t)n * (C_IN * HWSZ);

  int p = t & 63;                                   // lane
  int w = t >> 6;                                   // wave 0..15
  int g = __builtin_amdgcn_readfirstlane(w & 7);    // ck/oc-group, wave-uniform
  int ch = __builtin_amdgcn_readfirstlane(w >> 3);  // c-half, wave-uniform

  // ---- hoisted float2 staging descriptors (full 64-c chunk = 3840 f2) ----
  int srcOff[4];
  unsigned vbits = 0, wbits = 0;
  #pragma unroll
  for (int it = 0; it < 4; it++) {
    int e = t + it * 1024;
    int c = e / 60;
    int rem = e - c * 60;
    int row = rem / 10, pr = rem - row * 10;
    int gy = y0 - 1 + row;
    int gc0 = x0 - 2 + pr * 2;
    bool wr = (e < 3840);
    bool ok = wr & ((unsigned)gy < 64u) & ((unsigned)gc0 < 63u);  // pair fully in [0,63]
    srcOff[it] = ok ? (c * HWSZ + gy * 64 + gc0) : 0;
    vbits |= (ok ? 1u : 0u) << it;
    wbits |= (wr ? 1u : 0u) << it;
  }

  // padded-slot ownership: q0 = p (slots 0..63), q1 = p+60 (slots 60..119)
  int q1 = p + 60;
  int q1c = (q1 < 120) ? q1 : 119;                  // clamped read
  int r0q = p / 20,  c0q = p - r0q * 20;
  int r1q = q1c / 20, c1q = q1c - r1q * 20;
  bool val0 = (c0q >= 1) & (c0q <= 18);
  bool val1 = (q1 < 120) & (c1q >= 1) & (c1q <= 18);
  int toff0 = r0q * 24 + c0q - 1;                   // stride-24 tile offset
  int toff1 = r1q * 24 + c1q - 1;

  // packed accumulators: a0p[i2] = {ck 2*i2, ck 2*i2+1}
  f32x2 a0p[4], a1p[4];
  #pragma unroll
  for (int i2 = 0; i2 < 4; i2++) {
    f32x2 b;
    if (ch == 0) { b[0] = bc[g * 8 + i2 * 2]; b[1] = bc[g * 8 + i2 * 2 + 1]; }
    else         { b[0] = 0.f; b[1] = 0.f; }
    a0p[i2] = b; a1p[i2] = b;
  }

  // prefetch chunk 0; prologue: A <- chunk0, issue chunk1
  float2 rv[4];
  #pragma unroll
  for (int it = 0; it < 4; it++) rv[it] = *(const float2*)(xn + srcOff[it]);

  float* sA = s_mem;
  float* sB = s_mem + 7680;
  #pragma unroll
  for (int it = 0; it < 4; it++)
    if (wbits & (1u << it))
      *(float2*)(&sA[2 * t + it * 2048]) =
          (vbits & (1u << it)) ? rv[it] : make_float2(0.f, 0.f);
  {
    const float* xb = xn + (size_t)64 * HWSZ;
    #pragma unroll
    for (int it = 0; it < 4; it++) rv[it] = *(const float2*)(xb + srcOff[it]);
  }
  __syncthreads();

  for (int k = 0; k < 4; k++) {
    // stage next chunk into B (overlaps FMA of the active half)
    if (k < 3) {
      #pragma unroll
      for (int it = 0; it < 4; it++)
        if (wbits & (1u << it))
          *(float2*)(&sB[2 * t + it * 2048]) =
              (vbits & (1u << it)) ? rv[it] : make_float2(0.f, 0.f);
    }
    // issue chunk k+2 loads; latency hides under FMA phase
    if (k < 2) {
      const float* xb = xn + (size_t)(k + 2) * 64 * HWSZ;
      #pragma unroll
      for (int it = 0; it < 4; it++) rv[it] = *(const float2*)(xb + srcOff[it]);
    }
    // packed FMA over A by the matching c-half (wave-uniform branch)
    if ((k >> 1) == ch) {
      const float* wbase = wcT + (k * 64) * 64 + g * 8;
      #pragma unroll 4
      for (int c = 0; c < 64; c++) {
        float v0 = sA[c * 120 + p];
        float v1 = sA[c * 120 + q1c];
        const f32x2* w2 = (const f32x2*)(wbase + c * 64);   // 32B-aligned
        f32x2 v0b; v0b[0] = v0; v0b[1] = v0;
        f32x2 v1b; v1b[0] = v1; v1b[1] = v1;
        #pragma unroll
        for (int i2 = 0; i2 < 4; i2++) {
          a0p[i2] += v0b * w2[i2];
          a1p[i2] += v1b * w2[i2];
        }
      }
    }
    __syncthreads();
    float* tmp = sA; sA = sB; sB = tmp;
  }

  // combine c-half partials into s_tile (aliases dead staging mem).
  // ch1 writes; barrier; ch0 adds (carries bias). Overlap slots 60..63
  // have bit-identical values in both owners -> duplicate RMW value-safe.
  if (ch == 1) {
    if (val0) {
      #pragma unroll
      for (int i2 = 0; i2 < 4; i2++) {
        s_tile[(g * 8 + i2 * 2) * 144 + toff0]     = a0p[i2][0];
        s_tile[(g * 8 + i2 * 2 + 1) * 144 + toff0] = a0p[i2][1];
      }
    }
    if (val1) {
      #pragma unroll
      for (int i2 = 0; i2 < 4; i2++) {
        s_tile[(g * 8 + i2 * 2) * 144 + toff1]     = a1p[i2][0];
        s_tile[(g * 8 + i2 * 2 + 1) * 144 + toff1] = a1p[i2][1];
      }
    }
  }
  __syncthreads();
  if (ch == 0) {
    if (val0) {
      #pragma unroll
      for (int i2 = 0; i2 < 4; i2++) {
        int i0 = (g * 8 + i2 * 2) * 144 + toff0;
        int i1 = (g * 8 + i2 * 2 + 1) * 144 + toff0;
        s_tile[i0] = s_tile[i0] + a0p[i2][0];
        s_tile[i1] = s_tile[i1] + a0p[i2][1];
      }
    }
    if (val1) {
      #pragma unroll
      for (int i2 = 0; i2 < 4; i2++) {
        int i0 = (g * 8 + i2 * 2) * 144 + toff1;
        int i1 = (g * 8 + i2 * 2 + 1) * 144 + toff1;
        s_tile[i0] = s_tile[i0] + a1p[i2][0];
        s_tile[i1] = s_tile[i1] + a1p[i2][1];
      }
    }
  }
  __syncthreads();

  // ---- conv part: wave (g, ch) covers c in [ch*32, ch*32+32) ----
  // packed: acc01/acc23 as f32x2, acc4 scalar; weights from wT2 (aligned).
  int px = p & 15, py = p >> 4;
  f32x2 acc01; acc01[0] = 0.f; acc01[1] = 0.f;
  f32x2 acc23; acc23[0] = 0.f; acc23[1] = 0.f;
  float acc4 = 0.f;
  const float* tl0 = s_tile + py * 24 + px;
  int cb = ch * 32;

#define LOADWIN(dst, cidx)                                   \
  {                                                          \
    const float* tlc = tl0 + (cidx) * 144;                   \
    _Pragma("unroll")                                        \
    for (int tap = 0; tap < 9; tap++) {                      \
      int dy = tap / 3, dx = tap % 3;                        \
      dst[tap] = tlc[dy * 24 + dx];                          \
    }                                                        \
  }
#define FMAWIN(src, cidx)                                    \
  {                                                          \
    _Pragma("unroll")                                        \
    for (int tap = 0; tap < 9; tap++) {                      \
      float v = src[tap];                                    \
      const float* wp = wT2 + (((cidx) * 9 + tap) * 8 + g) * 6; \
      f32x2 w01 = *(const f32x2*)(wp);                       \
      f32x2 w23 = *(const f32x2*)(wp + 2);                   \
      float w4 = wp[4];                                      \
      f32x2 vb; vb[0] = v; vb[1] = v;                        \
      acc01 += vb * w01;                                     \
      acc23 += vb * w23;                                     \
      acc4 += v * w4;                                        \
    }                                                        \
  }

  float wa[9], wbuf[9];
  LOADWIN(wa, cb + 0)
  LOADWIN(wbuf, cb + 1)
  #pragma unroll 1
  for (int c = 0; c < 32; c += 2) {
    FMAWIN(wa, cb + c)
    if (c + 2 < 32) LOADWIN(wa, cb + c + 2)
    FMAWIN(wbuf, cb + c + 1)
    if (c + 3 < 32) LOADWIN(wbuf, cb + c + 3)
  }
#undef LOADWIN
#undef FMAWIN

  // s_res aliases s_tile: all reads done -> ch0 writes, ch1 accumulates
  __syncthreads();
  if (ch == 0) {
    s_res[(g * 5 + 0) * 64 + p] = acc01[0];
    s_res[(g * 5 + 1) * 64 + p] = acc01[1];
    s_res[(g * 5 + 2) * 64 + p] = acc23[0];
    s_res[(g * 5 + 3) * 64 + p] = acc23[1];
    s_res[(g * 5 + 4) * 64 + p] = acc4;
  }
  __syncthreads();
  if (ch == 1) {
    s_res[(g * 5 + 0) * 64 + p] += acc01[0];
    s_res[(g * 5 + 1) * 64 + p] += acc01[1];
    s_res[(g * 5 + 2) * 64 + p] += acc23[0];
    s_res[(g * 5 + 3) * 64 + p] += acc23[1];
    s_res[(g * 5 + 4) * 64 + p] += acc4;
  }
  __syncthreads();

  int hw = (y0 + py) * 64 + x0 + px;
  // offsets: 8 channels; ch0 wave g writes oc = g
  if (ch == 0)
    offb[(n * 8 + g) * HWSZ + hw] = s_res[g * 64 + p] + bo[g];
  // softmax over 25 kernel positions: threads 0..63, one pixel per lane
  if (t < 64) {
    float m[25], mx = -1e30f;
    #pragma unroll
    for (int k = 0; k < 25; k++) { m[k] = s_res[(8 + k) * 64 + p] + bk[k]; mx = fmaxf(mx, m[k]); }
    float s = 0.f;
    #pragma unroll
    for (int k = 0; k < 25; k++) { m[k] = __expf(m[k] - mx); s += m[k]; }
    float inv = 1.f / s;
    #pragma unroll
    for (int k = 0; k < 25; k++) maskb[(n * 25 + k) * HWSZ + hw] = m[k] * inv;
  }
}

// ---------------- Kernel C (v6): main CARAFE reassembly ----------------
// FROZEN at r5's 45.1us version (float2 staging, T14 prefetch, plain stores,
// no swizzle). See r5 notes: request-rate theory confirmed (62.4 -> 45.1).
__global__ __launch_bounds__(256, 4) void k_carafe(const float* __restrict__ x,
    const float* __restrict__ offb, const float* __restrict__ maskb,
    float* __restrict__ out) {
  __attribute__((aligned(16))) __shared__ float s_patch[32 * 202]; // 25856B; aliased as s_out [32][130]
  __attribute__((aligned(16))) __shared__ float s_kern[32 * 25 * 4]; // 12800B
  int t = threadIdx.x;
  int b = blockIdx.x;
  int n = b >> 8;
  int r = b & 255;
  int half = r & 1;
  int wq = (r >> 1) & 3;
  int aa = r >> 3;
  int a = aa + (aa & 16);                 // h base: bit4 == 0
  int yout = (a & 15) * 8 + wq * 2 + ((a >> 5) & 1);
  int w0 = wq * 16;
  int cbase = n * C_IN + half * 128;

  // ---- hoisted float2 staging descriptors (computed ONCE) ----
  int srcOff[13];          // channel-plane-relative src offset (pair base)
  int dstOff[13];          // LDS float index (8B aligned)
  unsigned vbits = 0;      // data-valid (in-bounds) mask
  unsigned wbits = 0;      // write-enable (e < 3200) mask
  #pragma unroll
  for (int it = 0; it < 13; it++) {
    int e = t + it * 256;
    int c = e / 100;
    int rem = e - c * 100;
    int rg = rem / 10;
    int c2 = rem - rg * 10;
    int row = (rg < 5) ? (a - 2 + rg) : (a + 9 + rg);
    int gc0 = w0 - 2 + c2 * 2;
    bool wr = (e < 3200);
    bool ok = wr & ((unsigned)row < 64u) & ((unsigned)gc0 < 64u);
    srcOff[it] = ok ? (c * HWSZ + row * 64 + gc0) : 0;
    dstOff[it] = wr ? 2 * (e + c) : 0;
    vbits |= (ok ? 1u : 0u) << it;
    wbits |= (wr ? 1u : 0u) << it;
  }

  // prefetch chunk 0 into registers (flies during phase 1)
  float2 rv[13];
  {
    const float* xn = x + (size_t)cbase * HWSZ;
    #pragma unroll
    for (int it = 0; it < 13; it++) rv[it] = *(const float2*)(xn + srcOff[it]);
  }

  // Phase 1: per-(pos,u) 25 resampled kernel weights -> LDS [p][tap][u]
  if (t < 128) {
    int p = t >> 2, u = t & 3;
    int hb = p >> 4, wl = p & 15;
    int h = a + hb * 16;
    int wcol = w0 + wl;
    float ox = offb[(n * 8 + u) * HWSZ + h * 64 + wcol];
    float oy = offb[(n * 8 + 4 + u) * HWSZ + h * 64 + wcol];
    float gx = fminf(fmaxf((float)wcol + ox, 0.f), 63.f);
    float gy = fminf(fmaxf((float)h + oy, 0.f), 63.f);
    float fx0 = floorf(gx), fy0 = floorf(gy);
    int x0 = (int)fx0, y0 = (int)fy0;
    float fx = gx - fx0, fy = gy - fy0;
    int x1 = min(x0 + 1, 63), y1 = min(y0 + 1, 63);
    float w11 = fx * fy;
    float w10 = fy - w11, w01 = fx - w11, w00 = 1.f - fx - fy + w11;
    const float* mb = maskb + n * (K2 * HWSZ);
    int i00 = y0 * 64 + x0, i01 = y0 * 64 + x1;
    int i10 = y1 * 64 + x0, i11 = y1 * 64 + x1;
    #pragma unroll 5
    for (int k = 0; k < 25; k++) {
      const float* mk = mb + k * HWSZ;
      float v = w00 * mk[i00] + w01 * mk[i01] + w10 * mk[i10] + w11 * mk[i11];
      s_kern[(p * 25 + k) * 4 + u] = v;
    }
  }

  int cl = t & 31, g = t >> 5;            // channel lane 0..31, pos-group 0..7
  int hb = g >> 2, wl0 = (g & 3) * 4;     // each group: 4 consecutive wl in one hb
  float* s_out = s_patch;                 // alias: [32][130] = 16640B <= 25856B

  for (int cc = 0; cc < 4; cc++) {
    __syncthreads();   // covers phase-1 (first iter) and staging-vs-store alias (later)
    // stage x patch from prefetched registers: 32 c x 10 rows x 20 cols
    #pragma unroll
    for (int it = 0; it < 13; it++) {
      if (wbits & (1u << it)) {
        float2 v = (vbits & (1u << it)) ? rv[it] : make_float2(0.f, 0.f);
        *(float2*)(&s_patch[dstOff[it]]) = v;   // ds_write_b64
      }
    }
    __syncthreads();
    // issue next chunk's loads NOW; latency hides under compute+store below
    if (cc < 3) {
      const float* xn = x + (size_t)(cbase + (cc + 1) * 32) * HWSZ;
      #pragma unroll
      for (int it = 0; it < 13; it++) rv[it] = *(const float2*)(xn + srcOff[it]);
    }
    // compute: thread (cl, g) -> 4 positions x 4 u; register row-cache over dy
    float acc[4][4];
    #pragma unroll
    for (int i = 0; i < 4; i++)
      acc[i][0] = acc[i][1] = acc[i][2] = acc[i][3] = 0.f;
    const float* pc = s_patch + cl * 202 + hb * 100 + wl0;
    #pragma unroll
    for (int dy = 0; dy < 5; dy++) {
      float r8[8];
      #pragma unroll
      for (int j = 0; j < 8; j++) r8[j] = pc[dy * 20 + j];
      #pragma unroll
      for (int pr = 0; pr < 4; pr++) {
        const float4* kp = (const float4*)(s_kern + (((g * 4 + pr) * 25) + dy * 5) * 4);
        #pragma unroll
        for (int dx = 0; dx < 5; dx++) {
          float f = r8[pr + dx];
          float4 k4 = kp[dx];
          acc[pr][0] += f * k4.x;
          acc[pr][1] += f * k4.y;
          acc[pr][2] += f * k4.z;
          acc[pr][3] += f * k4.w;
        }
      }
    }
    __syncthreads();
    // transpose through LDS: s_out[c][x] stride 130, x = wl*8 + u*2 + hb
    #pragma unroll
    for (int pr = 0; pr < 4; pr++) {
      int wl = wl0 + pr;
      #pragma unroll
      for (int u = 0; u < 4; u++) {
        int xo = wl * 8 + u * 2 + hb;
        s_out[cl * 130 + xo] = acc[pr][u];
      }
    }
    __syncthreads();
    // coalesced store: 32 channel-rows x 128 x at fixed yout
    float* obase = out + ((size_t)(cbase + cc * 32) * 128 + yout) * 128;
    #pragma unroll
    for (int it = 0; it < 4; it++) {
      int q2 = t + it * 256;
      int rowc = q2 >> 5;       // 0..31 (channel within chunk)
      int col4 = q2 & 31;       // float4 index within row
      const float* sp = s_out + rowc * 130 + col4 * 4;
      float4 v = make_float4(sp[0], sp[1], sp[2], sp[3]);
      *(float4*)(obase + (size_t)rowc * (128 * 128) + col4 * 4) = v;
    }
  }
}

extern "C" void kernel_launch(void* const* d_in, const int* in_sizes, int n_in,
                              void* d_out, int out_size, void* d_ws, size_t ws_size,
                              hipStream_t stream) {
  const float* x      = (const float*)d_in[0];
  const float* w_comp = (const float*)d_in[1];
  const float* b_comp = (const float*)d_in[2];
  const float* w_ker  = (const float*)d_in[3];
  const float* b_ker  = (const float*)d_in[4];
  const float* w_off  = (const float*)d_in[5];
  const float* b_off  = (const float*)d_in[6];
  float* out = (float*)d_out;
  float* ws = (float*)d_ws;
  float* wcT   = ws + WS_WCT;
  float* wT2   = ws + WS_WT2;
  float* offb  = ws + WS_OFF;
  float* maskb = ws + WS_MASK;

  hipLaunchKernelGGL(k_wt, dim3((NWT2 + NWC + 255) / 256), dim3(256), 0, stream,
                     w_ker, w_off, w_comp, wT2, wcT);
  hipLaunchKernelGGL(k_cs, dim3(64, 4), dim3(1024), 0, stream,
                     x, wcT, b_comp, wT2, b_ker, b_off, offb, maskb);
  hipLaunchKernelGGL(k_carafe, dim3(1024), dim3(256), 0, stream, x, offb, maskb, out);
}

// Round 14
// 173.163 us; speedup vs baseline: 1.0285x; 1.0285x over previous
//
#include <hip/hip_runtime.h>
#include <math.h>

#define NB 4
#define C_IN 256
#define CKC 64
#define HWSZ 4096   // 64*64
#define K2 25
#define NOC2 40     // 33 output chans padded to 40 (8 groups x 5)

// workspace layout (float offsets)
#define WS_CX    0                               // cx region DEAD (fusion); first 16384 floats host wcT
#define WS_OFF   (WS_CX + NB*CKC*HWSZ)          // 1048576
#define WS_MASK  (WS_OFF + NB*8*HWSZ)           // +131072
#define WS_WT    (WS_MASK + NB*K2*HWSZ)         // +409600

#define NWT (CKC * 9 * NOC2)    // 23040
#define NWC (C_IN * CKC)        // 16384

// ---------------- Kernel D: weight prep ----------------
// wT[c][tap][oc(40)] for the 3x3 convs; wcT[c][ck] for the compressor.
__global__ void k_wt(const float* __restrict__ wk, const float* __restrict__ wo,
                     const float* __restrict__ wc,
                     float* __restrict__ wT, float* __restrict__ wcT) {
  int i = blockIdx.x * 256 + threadIdx.x;
  if (i < NWT) {
    int oc = i % NOC2;
    int r = i / NOC2;        // r = c*9 + tap
    int tap = r % 9, c = r / 9;
    float v = 0.f;
    if (oc < 8)       v = wo[(oc * CKC + c) * 9 + tap];
    else if (oc < 33) v = wk[((oc - 8) * CKC + c) * 9 + tap];
    wT[i] = v;
  } else {
    int j = i - NWT;
    if (j < NWC) {
      int c = j >> 6, ck = j & 63;
      wcT[j] = wc[ck * C_IN + c];
    }
  }
}

// ---------------- Kernel B (v8): FUSED compress+conv+softmax, 16 waves ----
// grid (64,4) x 1024 thr: block = one 16x4 tile, 16 waves = 4 waves/SIMD.
// REVERTED to the r12-measured-best version (k_cs 53.2us, total 172.8us).
// r13 postmortem: f32x2 packing regressed to 58us -- VALUBusy is ~31%, so
// the VALU issue pipe was never the binding constraint; the kernel is
// stall-bound (LDS chains + scalar weight loads + barriers). Packing
// attacked a non-binding constraint and added broadcast overhead (same
// mistake class as r3's swizzle). This round is also the drift A/B:
// ~173 => r13 regression real; ~178 => drift band is +-5us.
__global__ __launch_bounds__(1024) void k_cs(const float* __restrict__ x,
    const float* __restrict__ wcT, const float* __restrict__ bc,
    const float* __restrict__ wT, const float* __restrict__ bk, const float* __restrict__ bo,
    float* __restrict__ offb, float* __restrict__ maskb) {
  __attribute__((aligned(16))) __shared__ float s_mem[15360];  // 61440B union
  // compress: s_A = s_mem[0..7679], s_B = s_mem[7680..15359]  (64c x 120)
  // conv:     s_tile[64][144] = s_mem[0..9215]
  // epilogue: s_res[NOC2*64]  = s_mem[0..2559]
  float* s_tile = s_mem;
  float* s_res  = s_mem;

  int t = threadIdx.x;
  int n = blockIdx.y;
  int tile = blockIdx.x;
  int x0 = (tile & 3) * 16, y0 = (tile >> 2) * 4;
  const float* xn = x + (size_t)n * (C_IN * HWSZ);

  int p = t & 63;                                   // lane
  int w = t >> 6;                                   // wave 0..15
  int g = __builtin_amdgcn_readfirstlane(w & 7);    // ck/oc-group, wave-uniform
  int ch = __builtin_amdgcn_readfirstlane(w >> 3);  // c-half, wave-uniform

  // ---- hoisted float2 staging descriptors (full 64-c chunk = 3840 f2) ----
  // pair e = t + it*1024; [c][120] layout (6 rows x 10 f2, 20-col pad from
  // x0-2); dst = 2*e. halo col j (gc = x0-1+j) -> staged col j+1.
  int srcOff[4];
  unsigned vbits = 0, wbits = 0;
  #pragma unroll
  for (int it = 0; it < 4; it++) {
    int e = t + it * 1024;
    int c = e / 60;
    int rem = e - c * 60;
    int row = rem / 10, pr = rem - row * 10;
    int gy = y0 - 1 + row;
    int gc0 = x0 - 2 + pr * 2;
    bool wr = (e < 3840);
    bool ok = wr & ((unsigned)gy < 64u) & ((unsigned)gc0 < 63u);  // pair fully in [0,63]
    srcOff[it] = ok ? (c * HWSZ + gy * 64 + gc0) : 0;
    vbits |= (ok ? 1u : 0u) << it;
    wbits |= (wr ? 1u : 0u) << it;
  }

  // padded-slot ownership: q0 = p (slots 0..63), q1 = p+60 (slots 60..119)
  int q1 = p + 60;
  int q1c = (q1 < 120) ? q1 : 119;                  // clamped read
  int r0q = p / 20,  c0q = p - r0q * 20;
  int r1q = q1c / 20, c1q = q1c - r1q * 20;
  bool val0 = (c0q >= 1) & (c0q <= 18);
  bool val1 = (q1 < 120) & (c1q >= 1) & (c1q <= 18);
  int toff0 = r0q * 24 + c0q - 1;                   // stride-24 tile offset
  int toff1 = r1q * 24 + c1q - 1;
  float a0[8], a1[8];
  #pragma unroll
  for (int i = 0; i < 8; i++) {
    float b = (ch == 0) ? bc[g * 8 + i] : 0.f;      // bias once (ch0 only)
    a0[i] = b; a1[i] = b;
  }

  // prefetch chunk 0; prologue: A <- chunk0, issue chunk1
  float2 rv[4];
  #pragma unroll
  for (int it = 0; it < 4; it++) rv[it] = *(const float2*)(xn + srcOff[it]);

  float* sA = s_mem;
  float* sB = s_mem + 7680;
  #pragma unroll
  for (int it = 0; it < 4; it++)
    if (wbits & (1u << it))
      *(float2*)(&sA[2 * t + it * 2048]) =
          (vbits & (1u << it)) ? rv[it] : make_float2(0.f, 0.f);
  {
    const float* xb = xn + (size_t)64 * HWSZ;
    #pragma unroll
    for (int it = 0; it < 4; it++) rv[it] = *(const float2*)(xb + srcOff[it]);
  }
  __syncthreads();

  for (int k = 0; k < 4; k++) {
    // stage next chunk into B (overlaps FMA of the active half)
    if (k < 3) {
      #pragma unroll
      for (int it = 0; it < 4; it++)
        if (wbits & (1u << it))
          *(float2*)(&sB[2 * t + it * 2048]) =
              (vbits & (1u << it)) ? rv[it] : make_float2(0.f, 0.f);
    }
    // issue chunk k+2 loads; latency hides under FMA phase
    if (k < 2) {
      const float* xb = xn + (size_t)(k + 2) * 64 * HWSZ;
      #pragma unroll
      for (int it = 0; it < 4; it++) rv[it] = *(const float2*)(xb + srcOff[it]);
    }
    // FMA over A by the matching c-half (wave-uniform branch)
    if ((k >> 1) == ch) {
      const float* wbase = wcT + (k * 64) * 64 + g * 8;
      #pragma unroll 4
      for (int c = 0; c < 64; c++) {
        float v0 = sA[c * 120 + p];
        float v1 = sA[c * 120 + q1c];
        const float* wp = wbase + c * 64;
        #pragma unroll
        for (int i = 0; i < 8; i++) { a0[i] += v0 * wp[i]; a1[i] += v1 * wp[i]; }
      }
    }
    __syncthreads();
    float* tmp = sA; sA = sB; sB = tmp;
  }

  // combine c-half partials into s_tile (aliases dead staging mem).
  // ch1 writes its partials to the final slots; barrier; ch0 adds its own
  // (which carry the bias). Overlap slots 60..63 have bit-identical values
  // in both owners -> duplicate RMW is value-safe.
  if (ch == 1) {
    if (val0) {
      #pragma unroll
      for (int i = 0; i < 8; i++) s_tile[(g * 8 + i) * 144 + toff0] = a0[i];
    }
    if (val1) {
      #pragma unroll
      for (int i = 0; i < 8; i++) s_tile[(g * 8 + i) * 144 + toff1] = a1[i];
    }
  }
  __syncthreads();
  if (ch == 0) {
    if (val0) {
      #pragma unroll
      for (int i = 0; i < 8; i++) {
        int idx = (g * 8 + i) * 144 + toff0;
        s_tile[idx] = s_tile[idx] + a0[i];
      }
    }
    if (val1) {
      #pragma unroll
      for (int i = 0; i < 8; i++) {
        int idx = (g * 8 + i) * 144 + toff1;
        s_tile[idx] = s_tile[idx] + a1[i];
      }
    }
  }
  __syncthreads();

  // ---- conv part: wave (g, ch) covers c in [ch*32, ch*32+32) ----
  int px = p & 15, py = p >> 4;
  float acc[5];
  #pragma unroll
  for (int j = 0; j < 5; j++) acc[j] = 0.f;
  const float* wg = wT + g * 5;
  const float* tl0 = s_tile + py * 24 + px;
  int cb = ch * 32;

#define LOADWIN(dst, cidx)                                   \
  {                                                          \
    const float* tlc = tl0 + (cidx) * 144;                   \
    _Pragma("unroll")                                        \
    for (int tap = 0; tap < 9; tap++) {                      \
      int dy = tap / 3, dx = tap % 3;                        \
      dst[tap] = tlc[dy * 24 + dx];                          \
    }                                                        \
  }
#define FMAWIN(src, cidx)                                    \
  {                                                          \
    const float* wc9 = wg + (cidx) * 9 * NOC2;               \
    _Pragma("unroll")                                        \
    for (int tap = 0; tap < 9; tap++) {                      \
      float v = src[tap];                                    \
      const float* wp = wc9 + tap * NOC2;                    \
      _Pragma("unroll")                                      \
      for (int j = 0; j < 5; j++) acc[j] += v * wp[j];       \
    }                                                        \
  }

  float wa[9], wbuf[9];
  LOADWIN(wa, cb + 0)
  LOADWIN(wbuf, cb + 1)
  #pragma unroll 1
  for (int c = 0; c < 32; c += 2) {
    FMAWIN(wa, cb + c)
    if (c + 2 < 32) LOADWIN(wa, cb + c + 2)
    FMAWIN(wbuf, cb + c + 1)
    if (c + 3 < 32) LOADWIN(wbuf, cb + c + 3)
  }
#undef LOADWIN
#undef FMAWIN

  // s_res aliases s_tile: all reads done -> ch0 writes, ch1 accumulates
  __syncthreads();
  if (ch == 0) {
    #pragma unroll
    for (int j = 0; j < 5; j++) s_res[(g * 5 + j) * 64 + p] = acc[j];
  }
  __syncthreads();
  if (ch == 1) {
    #pragma unroll
    for (int j = 0; j < 5; j++) s_res[(g * 5 + j) * 64 + p] += acc[j];
  }
  __syncthreads();

  int hw = (y0 + py) * 64 + x0 + px;
  // offsets: 8 channels; ch0 wave g writes oc = g
  if (ch == 0)
    offb[(n * 8 + g) * HWSZ + hw] = s_res[g * 64 + p] + bo[g];
  // softmax over 25 kernel positions: threads 0..63, one pixel per lane
  if (t < 64) {
    float m[25], mx = -1e30f;
    #pragma unroll
    for (int k = 0; k < 25; k++) { m[k] = s_res[(8 + k) * 64 + p] + bk[k]; mx = fmaxf(mx, m[k]); }
    float s = 0.f;
    #pragma unroll
    for (int k = 0; k < 25; k++) { m[k] = __expf(m[k] - mx); s += m[k]; }
    float inv = 1.f / s;
    #pragma unroll
    for (int k = 0; k < 25; k++) maskb[(n * 25 + k) * HWSZ + hw] = m[k] * inv;
  }
}

// ---------------- Kernel C (v6): main CARAFE reassembly ----------------
// FROZEN at r5's 45.1us version (float2 staging, T14 prefetch, plain stores,
// no swizzle). See r5 notes: request-rate theory confirmed (62.4 -> 45.1).
__global__ __launch_bounds__(256, 4) void k_carafe(const float* __restrict__ x,
    const float* __restrict__ offb, const float* __restrict__ maskb,
    float* __restrict__ out) {
  __attribute__((aligned(16))) __shared__ float s_patch[32 * 202]; // 25856B; aliased as s_out [32][130]
  __attribute__((aligned(16))) __shared__ float s_kern[32 * 25 * 4]; // 12800B
  int t = threadIdx.x;
  int b = blockIdx.x;
  int n = b >> 8;
  int r = b & 255;
  int half = r & 1;
  int wq = (r >> 1) & 3;
  int aa = r >> 3;
  int a = aa + (aa & 16);                 // h base: bit4 == 0
  int yout = (a & 15) * 8 + wq * 2 + ((a >> 5) & 1);
  int w0 = wq * 16;
  int cbase = n * C_IN + half * 128;

  // ---- hoisted float2 staging descriptors (computed ONCE) ----
  int srcOff[13];          // channel-plane-relative src offset (pair base)
  int dstOff[13];          // LDS float index (8B aligned)
  unsigned vbits = 0;      // data-valid (in-bounds) mask
  unsigned wbits = 0;      // write-enable (e < 3200) mask
  #pragma unroll
  for (int it = 0; it < 13; it++) {
    int e = t + it * 256;
    int c = e / 100;
    int rem = e - c * 100;
    int rg = rem / 10;
    int c2 = rem - rg * 10;
    int row = (rg < 5) ? (a - 2 + rg) : (a + 9 + rg);
    int gc0 = w0 - 2 + c2 * 2;
    bool wr = (e < 3200);
    bool ok = wr & ((unsigned)row < 64u) & ((unsigned)gc0 < 64u);
    srcOff[it] = ok ? (c * HWSZ + row * 64 + gc0) : 0;
    dstOff[it] = wr ? 2 * (e + c) : 0;
    vbits |= (ok ? 1u : 0u) << it;
    wbits |= (wr ? 1u : 0u) << it;
  }

  // prefetch chunk 0 into registers (flies during phase 1)
  float2 rv[13];
  {
    const float* xn = x + (size_t)cbase * HWSZ;
    #pragma unroll
    for (int it = 0; it < 13; it++) rv[it] = *(const float2*)(xn + srcOff[it]);
  }

  // Phase 1: per-(pos,u) 25 resampled kernel weights -> LDS [p][tap][u]
  if (t < 128) {
    int p = t >> 2, u = t & 3;
    int hb = p >> 4, wl = p & 15;
    int h = a + hb * 16;
    int wcol = w0 + wl;
    float ox = offb[(n * 8 + u) * HWSZ + h * 64 + wcol];
    float oy = offb[(n * 8 + 4 + u) * HWSZ + h * 64 + wcol];
    float gx = fminf(fmaxf((float)wcol + ox, 0.f), 63.f);
    float gy = fminf(fmaxf((float)h + oy, 0.f), 63.f);
    float fx0 = floorf(gx), fy0 = floorf(gy);
    int x0 = (int)fx0, y0 = (int)fy0;
    float fx = gx - fx0, fy = gy - fy0;
    int x1 = min(x0 + 1, 63), y1 = min(y0 + 1, 63);
    float w11 = fx * fy;
    float w10 = fy - w11, w01 = fx - w11, w00 = 1.f - fx - fy + w11;
    const float* mb = maskb + n * (K2 * HWSZ);
    int i00 = y0 * 64 + x0, i01 = y0 * 64 + x1;
    int i10 = y1 * 64 + x0, i11 = y1 * 64 + x1;
    #pragma unroll 5
    for (int k = 0; k < 25; k++) {
      const float* mk = mb + k * HWSZ;
      float v = w00 * mk[i00] + w01 * mk[i01] + w10 * mk[i10] + w11 * mk[i11];
      s_kern[(p * 25 + k) * 4 + u] = v;
    }
  }

  int cl = t & 31, g = t >> 5;            // channel lane 0..31, pos-group 0..7
  int hb = g >> 2, wl0 = (g & 3) * 4;     // each group: 4 consecutive wl in one hb
  float* s_out = s_patch;                 // alias: [32][130] = 16640B <= 25856B

  for (int cc = 0; cc < 4; cc++) {
    __syncthreads();   // covers phase-1 (first iter) and staging-vs-store alias (later)
    // stage x patch from prefetched registers: 32 c x 10 rows x 20 cols
    #pragma unroll
    for (int it = 0; it < 13; it++) {
      if (wbits & (1u << it)) {
        float2 v = (vbits & (1u << it)) ? rv[it] : make_float2(0.f, 0.f);
        *(float2*)(&s_patch[dstOff[it]]) = v;   // ds_write_b64
      }
    }
    __syncthreads();
    // issue next chunk's loads NOW; latency hides under compute+store below
    if (cc < 3) {
      const float* xn = x + (size_t)(cbase + (cc + 1) * 32) * HWSZ;
      #pragma unroll
      for (int it = 0; it < 13; it++) rv[it] = *(const float2*)(xn + srcOff[it]);
    }
    // compute: thread (cl, g) -> 4 positions x 4 u; register row-cache over dy
    float acc[4][4];
    #pragma unroll
    for (int i = 0; i < 4; i++)
      acc[i][0] = acc[i][1] = acc[i][2] = acc[i][3] = 0.f;
    const float* pc = s_patch + cl * 202 + hb * 100 + wl0;
    #pragma unroll
    for (int dy = 0; dy < 5; dy++) {
      float r8[8];
      #pragma unroll
      for (int j = 0; j < 8; j++) r8[j] = pc[dy * 20 + j];
      #pragma unroll
      for (int pr = 0; pr < 4; pr++) {
        const float4* kp = (const float4*)(s_kern + (((g * 4 + pr) * 25) + dy * 5) * 4);
        #pragma unroll
        for (int dx = 0; dx < 5; dx++) {
          float f = r8[pr + dx];
          float4 k4 = kp[dx];
          acc[pr][0] += f * k4.x;
          acc[pr][1] += f * k4.y;
          acc[pr][2] += f * k4.z;
          acc[pr][3] += f * k4.w;
        }
      }
    }
    __syncthreads();
    // transpose through LDS: s_out[c][x] stride 130, x = wl*8 + u*2 + hb
    #pragma unroll
    for (int pr = 0; pr < 4; pr++) {
      int wl = wl0 + pr;
      #pragma unroll
      for (int u = 0; u < 4; u++) {
        int xo = wl * 8 + u * 2 + hb;
        s_out[cl * 130 + xo] = acc[pr][u];
      }
    }
    __syncthreads();
    // coalesced store: 32 channel-rows x 128 x at fixed yout
    float* obase = out + ((size_t)(cbase + cc * 32) * 128 + yout) * 128;
    #pragma unroll
    for (int it = 0; it < 4; it++) {
      int q2 = t + it * 256;
      int rowc = q2 >> 5;       // 0..31 (channel within chunk)
      int col4 = q2 & 31;       // float4 index within row
      const float* sp = s_out + rowc * 130 + col4 * 4;
      float4 v = make_float4(sp[0], sp[1], sp[2], sp[3]);
      *(float4*)(obase + (size_t)rowc * (128 * 128) + col4 * 4) = v;
    }
  }
}

extern "C" void kernel_launch(void* const* d_in, const int* in_sizes, int n_in,
                              void* d_out, int out_size, void* d_ws, size_t ws_size,
                              hipStream_t stream) {
  const float* x      = (const float*)d_in[0];
  const float* w_comp = (const float*)d_in[1];
  const float* b_comp = (const float*)d_in[2];
  const float* w_ker  = (const float*)d_in[3];
  const float* b_ker  = (const float*)d_in[4];
  const float* w_off  = (const float*)d_in[5];
  const float* b_off  = (const float*)d_in[6];
  float* out = (float*)d_out;
  float* ws = (float*)d_ws;
  float* offb  = ws + WS_OFF;
  float* maskb = ws + WS_MASK;
  float* wT    = ws + WS_WT;
  float* wcT   = ws + WS_CX;   // cx region is dead post-fusion; wcT lives there

  hipLaunchKernelGGL(k_wt, dim3((NWT + NWC + 255) / 256), dim3(256), 0, stream,
                     w_ker, w_off, w_comp, wT, wcT);
  hipLaunchKernelGGL(k_cs, dim3(64, 4), dim3(1024), 0, stream,
                     x, wcT, b_comp, wT, b_ker, b_off, offb, maskb);
  hipLaunchKernelGGL(k_carafe, dim3(1024), dim3(256), 0, stream, x, offb, maskb, out);
}

// Round 15
// 172.662 us; speedup vs baseline: 1.0315x; 1.0029x over previous
//
#include <hip/hip_runtime.h>
#include <math.h>

#define NB 4
#define C_IN 256
#define CKC 64
#define HWSZ 4096   // 64*64
#define K2 25
#define NOC2 40     // 33 output chans padded to 40 (8 groups x 5)

// workspace layout (float offsets)
#define WS_CX    0                               // cx region DEAD (fusion); first 16384 floats host wcT
#define WS_OFF   (WS_CX + NB*CKC*HWSZ)          // 1048576
#define WS_MASK  (WS_OFF + NB*8*HWSZ)           // +131072
#define WS_WT    (WS_MASK + NB*K2*HWSZ)         // +409600

#define NWT (CKC * 9 * NOC2)    // 23040
#define NWC (C_IN * CKC)        // 16384

// LDS-only barrier: __syncthreads() emits "s_waitcnt vmcnt(0) lgkmcnt(0)"
// before s_barrier (m97 asm evidence), force-draining in-flight global
// prefetch loads and output stores that nothing at the barrier depends on.
// Every barrier in k_cs/k_carafe has only LDS cross-wave deps (audited:
// global-load -> ds_write deps are auto-enforced by compiler vmcnt-before-
// use on the register). lgkmcnt(0) + compiler memory fence preserves all
// LDS ordering; vmem stays in flight across the barrier (T4-lite).
#define BARRIER_LDS() do { \
    asm volatile("s_waitcnt lgkmcnt(0)" ::: "memory"); \
    __builtin_amdgcn_s_barrier(); \
  } while (0)

// ---------------- Kernel D: weight prep ----------------
// wT[c][tap][oc(40)] for the 3x3 convs; wcT[c][ck] for the compressor.
__global__ void k_wt(const float* __restrict__ wk, const float* __restrict__ wo,
                     const float* __restrict__ wc,
                     float* __restrict__ wT, float* __restrict__ wcT) {
  int i = blockIdx.x * 256 + threadIdx.x;
  if (i < NWT) {
    int oc = i % NOC2;
    int r = i / NOC2;        // r = c*9 + tap
    int tap = r % 9, c = r / 9;
    float v = 0.f;
    if (oc < 8)       v = wo[(oc * CKC + c) * 9 + tap];
    else if (oc < 33) v = wk[((oc - 8) * CKC + c) * 9 + tap];
    wT[i] = v;
  } else {
    int j = i - NWT;
    if (j < NWC) {
      int c = j >> 6, ck = j & 63;
      wcT[j] = wc[ck * C_IN + c];
    }
  }
}

// ---------------- Kernel B (v10): FUSED compress+conv+softmax, 16 waves ----
// grid (64,4) x 1024 thr: block = one 16x4 tile, 16 waves = 4 waves/SIMD.
// = r12/r14-verified v8 structure (53.2us) with BARRIER_LDS replacing
// __syncthreads: removes ~10 vmcnt(0) drains that were force-completing
// the T14 prefetch loads at each barrier.
__global__ __launch_bounds__(1024) void k_cs(const float* __restrict__ x,
    const float* __restrict__ wcT, const float* __restrict__ bc,
    const float* __restrict__ wT, const float* __restrict__ bk, const float* __restrict__ bo,
    float* __restrict__ offb, float* __restrict__ maskb) {
  __attribute__((aligned(16))) __shared__ float s_mem[15360];  // 61440B union
  // compress: s_A = s_mem[0..7679], s_B = s_mem[7680..15359]  (64c x 120)
  // conv:     s_tile[64][144] = s_mem[0..9215]
  // epilogue: s_res[NOC2*64]  = s_mem[0..2559]
  float* s_tile = s_mem;
  float* s_res  = s_mem;

  int t = threadIdx.x;
  int n = blockIdx.y;
  int tile = blockIdx.x;
  int x0 = (tile & 3) * 16, y0 = (tile >> 2) * 4;
  const float* xn = x + (size_t)n * (C_IN * HWSZ);

  int p = t & 63;                                   // lane
  int w = t >> 6;                                   // wave 0..15
  int g = __builtin_amdgcn_readfirstlane(w & 7);    // ck/oc-group, wave-uniform
  int ch = __builtin_amdgcn_readfirstlane(w >> 3);  // c-half, wave-uniform

  // ---- hoisted float2 staging descriptors (full 64-c chunk = 3840 f2) ----
  int srcOff[4];
  unsigned vbits = 0, wbits = 0;
  #pragma unroll
  for (int it = 0; it < 4; it++) {
    int e = t + it * 1024;
    int c = e / 60;
    int rem = e - c * 60;
    int row = rem / 10, pr = rem - row * 10;
    int gy = y0 - 1 + row;
    int gc0 = x0 - 2 + pr * 2;
    bool wr = (e < 3840);
    bool ok = wr & ((unsigned)gy < 64u) & ((unsigned)gc0 < 63u);  // pair fully in [0,63]
    srcOff[it] = ok ? (c * HWSZ + gy * 64 + gc0) : 0;
    vbits |= (ok ? 1u : 0u) << it;
    wbits |= (wr ? 1u : 0u) << it;
  }

  // padded-slot ownership: q0 = p (slots 0..63), q1 = p+60 (slots 60..119)
  int q1 = p + 60;
  int q1c = (q1 < 120) ? q1 : 119;                  // clamped read
  int r0q = p / 20,  c0q = p - r0q * 20;
  int r1q = q1c / 20, c1q = q1c - r1q * 20;
  bool val0 = (c0q >= 1) & (c0q <= 18);
  bool val1 = (q1 < 120) & (c1q >= 1) & (c1q <= 18);
  int toff0 = r0q * 24 + c0q - 1;                   // stride-24 tile offset
  int toff1 = r1q * 24 + c1q - 1;
  float a0[8], a1[8];
  #pragma unroll
  for (int i = 0; i < 8; i++) {
    float b = (ch == 0) ? bc[g * 8 + i] : 0.f;      // bias once (ch0 only)
    a0[i] = b; a1[i] = b;
  }

  // prefetch chunk 0; prologue: A <- chunk0, issue chunk1
  float2 rv[4];
  #pragma unroll
  for (int it = 0; it < 4; it++) rv[it] = *(const float2*)(xn + srcOff[it]);

  float* sA = s_mem;
  float* sB = s_mem + 7680;
  #pragma unroll
  for (int it = 0; it < 4; it++)
    if (wbits & (1u << it))
      *(float2*)(&sA[2 * t + it * 2048]) =
          (vbits & (1u << it)) ? rv[it] : make_float2(0.f, 0.f);
  {
    const float* xb = xn + (size_t)64 * HWSZ;
    #pragma unroll
    for (int it = 0; it < 4; it++) rv[it] = *(const float2*)(xb + srcOff[it]);
  }
  BARRIER_LDS();

  for (int k = 0; k < 4; k++) {
    // stage next chunk into B (overlaps FMA of the active half)
    if (k < 3) {
      #pragma unroll
      for (int it = 0; it < 4; it++)
        if (wbits & (1u << it))
          *(float2*)(&sB[2 * t + it * 2048]) =
              (vbits & (1u << it)) ? rv[it] : make_float2(0.f, 0.f);
    }
    // issue chunk k+2 loads; latency hides under FMA phase (and now
    // survives across barriers instead of being vmcnt(0)-drained)
    if (k < 2) {
      const float* xb = xn + (size_t)(k + 2) * 64 * HWSZ;
      #pragma unroll
      for (int it = 0; it < 4; it++) rv[it] = *(const float2*)(xb + srcOff[it]);
    }
    // FMA over A by the matching c-half (wave-uniform branch)
    if ((k >> 1) == ch) {
      const float* wbase = wcT + (k * 64) * 64 + g * 8;
      #pragma unroll 4
      for (int c = 0; c < 64; c++) {
        float v0 = sA[c * 120 + p];
        float v1 = sA[c * 120 + q1c];
        const float* wp = wbase + c * 64;
        #pragma unroll
        for (int i = 0; i < 8; i++) { a0[i] += v0 * wp[i]; a1[i] += v1 * wp[i]; }
      }
    }
    BARRIER_LDS();
    float* tmp = sA; sA = sB; sB = tmp;
  }

  // combine c-half partials into s_tile (aliases dead staging mem).
  // ch1 writes its partials to the final slots; barrier; ch0 adds its own
  // (which carry the bias). Overlap slots 60..63 have bit-identical values
  // in both owners -> duplicate RMW is value-safe.
  if (ch == 1) {
    if (val0) {
      #pragma unroll
      for (int i = 0; i < 8; i++) s_tile[(g * 8 + i) * 144 + toff0] = a0[i];
    }
    if (val1) {
      #pragma unroll
      for (int i = 0; i < 8; i++) s_tile[(g * 8 + i) * 144 + toff1] = a1[i];
    }
  }
  BARRIER_LDS();
  if (ch == 0) {
    if (val0) {
      #pragma unroll
      for (int i = 0; i < 8; i++) {
        int idx = (g * 8 + i) * 144 + toff0;
        s_tile[idx] = s_tile[idx] + a0[i];
      }
    }
    if (val1) {
      #pragma unroll
      for (int i = 0; i < 8; i++) {
        int idx = (g * 8 + i) * 144 + toff1;
        s_tile[idx] = s_tile[idx] + a1[i];
      }
    }
  }
  BARRIER_LDS();

  // ---- conv part: wave (g, ch) covers c in [ch*32, ch*32+32) ----
  int px = p & 15, py = p >> 4;
  float acc[5];
  #pragma unroll
  for (int j = 0; j < 5; j++) acc[j] = 0.f;
  const float* wg = wT + g * 5;
  const float* tl0 = s_tile + py * 24 + px;
  int cb = ch * 32;

#define LOADWIN(dst, cidx)                                   \
  {                                                          \
    const float* tlc = tl0 + (cidx) * 144;                   \
    _Pragma("unroll")                                        \
    for (int tap = 0; tap < 9; tap++) {                      \
      int dy = tap / 3, dx = tap % 3;                        \
      dst[tap] = tlc[dy * 24 + dx];                          \
    }                                                        \
  }
#define FMAWIN(src, cidx)                                    \
  {                                                          \
    const float* wc9 = wg + (cidx) * 9 * NOC2;               \
    _Pragma("unroll")                                        \
    for (int tap = 0; tap < 9; tap++) {                      \
      float v = src[tap];                                    \
      const float* wp = wc9 + tap * NOC2;                    \
      _Pragma("unroll")                                      \
      for (int j = 0; j < 5; j++) acc[j] += v * wp[j];       \
    }                                                        \
  }

  float wa[9], wbuf[9];
  LOADWIN(wa, cb + 0)
  LOADWIN(wbuf, cb + 1)
  #pragma unroll 1
  for (int c = 0; c < 32; c += 2) {
    FMAWIN(wa, cb + c)
    if (c + 2 < 32) LOADWIN(wa, cb + c + 2)
    FMAWIN(wbuf, cb + c + 1)
    if (c + 3 < 32) LOADWIN(wbuf, cb + c + 3)
  }
#undef LOADWIN
#undef FMAWIN

  // s_res aliases s_tile: all reads done -> ch0 writes, ch1 accumulates
  BARRIER_LDS();
  if (ch == 0) {
    #pragma unroll
    for (int j = 0; j < 5; j++) s_res[(g * 5 + j) * 64 + p] = acc[j];
  }
  BARRIER_LDS();
  if (ch == 1) {
    #pragma unroll
    for (int j = 0; j < 5; j++) s_res[(g * 5 + j) * 64 + p] += acc[j];
  }
  BARRIER_LDS();

  int hw = (y0 + py) * 64 + x0 + px;
  // offsets: 8 channels; ch0 wave g writes oc = g
  if (ch == 0)
    offb[(n * 8 + g) * HWSZ + hw] = s_res[g * 64 + p] + bo[g];
  // softmax over 25 kernel positions: threads 0..63, one pixel per lane
  if (t < 64) {
    float m[25], mx = -1e30f;
    #pragma unroll
    for (int k = 0; k < 25; k++) { m[k] = s_res[(8 + k) * 64 + p] + bk[k]; mx = fmaxf(mx, m[k]); }
    float s = 0.f;
    #pragma unroll
    for (int k = 0; k < 25; k++) { m[k] = __expf(m[k] - mx); s += m[k]; }
    float inv = 1.f / s;
    #pragma unroll
    for (int k = 0; k < 25; k++) maskb[(n * 25 + k) * HWSZ + hw] = m[k] * inv;
  }
}

// ---------------- Kernel C (v7): main CARAFE reassembly ----------------
// = r5-verified v6 structure (45.1us: float2 staging, T14 prefetch, plain
// stores, no swizzle) with BARRIER_LDS replacing __syncthreads: removes 16
// vmcnt(0) drains (4/chunk) that were force-completing the prefetch loads
// and output stores at every phase boundary.
__global__ __launch_bounds__(256, 4) void k_carafe(const float* __restrict__ x,
    const float* __restrict__ offb, const float* __restrict__ maskb,
    float* __restrict__ out) {
  __attribute__((aligned(16))) __shared__ float s_patch[32 * 202]; // 25856B; aliased as s_out [32][130]
  __attribute__((aligned(16))) __shared__ float s_kern[32 * 25 * 4]; // 12800B
  int t = threadIdx.x;
  int b = blockIdx.x;
  int n = b >> 8;
  int r = b & 255;
  int half = r & 1;
  int wq = (r >> 1) & 3;
  int aa = r >> 3;
  int a = aa + (aa & 16);                 // h base: bit4 == 0
  int yout = (a & 15) * 8 + wq * 2 + ((a >> 5) & 1);
  int w0 = wq * 16;
  int cbase = n * C_IN + half * 128;

  // ---- hoisted float2 staging descriptors (computed ONCE) ----
  int srcOff[13];          // channel-plane-relative src offset (pair base)
  int dstOff[13];          // LDS float index (8B aligned)
  unsigned vbits = 0;      // data-valid (in-bounds) mask
  unsigned wbits = 0;      // write-enable (e < 3200) mask
  #pragma unroll
  for (int it = 0; it < 13; it++) {
    int e = t + it * 256;
    int c = e / 100;
    int rem = e - c * 100;
    int rg = rem / 10;
    int c2 = rem - rg * 10;
    int row = (rg < 5) ? (a - 2 + rg) : (a + 9 + rg);
    int gc0 = w0 - 2 + c2 * 2;
    bool wr = (e < 3200);
    bool ok = wr & ((unsigned)row < 64u) & ((unsigned)gc0 < 64u);
    srcOff[it] = ok ? (c * HWSZ + row * 64 + gc0) : 0;
    dstOff[it] = wr ? 2 * (e + c) : 0;
    vbits |= (ok ? 1u : 0u) << it;
    wbits |= (wr ? 1u : 0u) << it;
  }

  // prefetch chunk 0 into registers (flies during phase 1)
  float2 rv[13];
  {
    const float* xn = x + (size_t)cbase * HWSZ;
    #pragma unroll
    for (int it = 0; it < 13; it++) rv[it] = *(const float2*)(xn + srcOff[it]);
  }

  // Phase 1: per-(pos,u) 25 resampled kernel weights -> LDS [p][tap][u]
  if (t < 128) {
    int p = t >> 2, u = t & 3;
    int hb = p >> 4, wl = p & 15;
    int h = a + hb * 16;
    int wcol = w0 + wl;
    float ox = offb[(n * 8 + u) * HWSZ + h * 64 + wcol];
    float oy = offb[(n * 8 + 4 + u) * HWSZ + h * 64 + wcol];
    float gx = fminf(fmaxf((float)wcol + ox, 0.f), 63.f);
    float gy = fminf(fmaxf((float)h + oy, 0.f), 63.f);
    float fx0 = floorf(gx), fy0 = floorf(gy);
    int x0 = (int)fx0, y0 = (int)fy0;
    float fx = gx - fx0, fy = gy - fy0;
    int x1 = min(x0 + 1, 63), y1 = min(y0 + 1, 63);
    float w11 = fx * fy;
    float w10 = fy - w11, w01 = fx - w11, w00 = 1.f - fx - fy + w11;
    const float* mb = maskb + n * (K2 * HWSZ);
    int i00 = y0 * 64 + x0, i01 = y0 * 64 + x1;
    int i10 = y1 * 64 + x0, i11 = y1 * 64 + x1;
    #pragma unroll 5
    for (int k = 0; k < 25; k++) {
      const float* mk = mb + k * HWSZ;
      float v = w00 * mk[i00] + w01 * mk[i01] + w10 * mk[i10] + w11 * mk[i11];
      s_kern[(p * 25 + k) * 4 + u] = v;
    }
  }

  int cl = t & 31, g = t >> 5;            // channel lane 0..31, pos-group 0..7
  int hb = g >> 2, wl0 = (g & 3) * 4;     // each group: 4 consecutive wl in one hb
  float* s_out = s_patch;                 // alias: [32][130] = 16640B <= 25856B

  for (int cc = 0; cc < 4; cc++) {
    BARRIER_LDS();   // covers phase-1 (first iter) and staging-vs-store alias (later)
    // stage x patch from prefetched registers: 32 c x 10 rows x 20 cols
    #pragma unroll
    for (int it = 0; it < 13; it++) {
      if (wbits & (1u << it)) {
        float2 v = (vbits & (1u << it)) ? rv[it] : make_float2(0.f, 0.f);
        *(float2*)(&s_patch[dstOff[it]]) = v;   // ds_write_b64
      }
    }
    BARRIER_LDS();
    // issue next chunk's loads NOW; latency hides under compute+store below
    // (and survives the next barriers instead of being vmcnt(0)-drained)
    if (cc < 3) {
      const float* xn = x + (size_t)(cbase + (cc + 1) * 32) * HWSZ;
      #pragma unroll
      for (int it = 0; it < 13; it++) rv[it] = *(const float2*)(xn + srcOff[it]);
    }
    // compute: thread (cl, g) -> 4 positions x 4 u; register row-cache over dy
    float acc[4][4];
    #pragma unroll
    for (int i = 0; i < 4; i++)
      acc[i][0] = acc[i][1] = acc[i][2] = acc[i][3] = 0.f;
    const float* pc = s_patch + cl * 202 + hb * 100 + wl0;
    #pragma unroll
    for (int dy = 0; dy < 5; dy++) {
      float r8[8];
      #pragma unroll
      for (int j = 0; j < 8; j++) r8[j] = pc[dy * 20 + j];
      #pragma unroll
      for (int pr = 0; pr < 4; pr++) {
        const float4* kp = (const float4*)(s_kern + (((g * 4 + pr) * 25) + dy * 5) * 4);
        #pragma unroll
        for (int dx = 0; dx < 5; dx++) {
          float f = r8[pr + dx];
          float4 k4 = kp[dx];
          acc[pr][0] += f * k4.x;
          acc[pr][1] += f * k4.y;
          acc[pr][2] += f * k4.z;
          acc[pr][3] += f * k4.w;
        }
      }
    }
    BARRIER_LDS();
    // transpose through LDS: s_out[c][x] stride 130, x = wl*8 + u*2 + hb
    #pragma unroll
    for (int pr = 0; pr < 4; pr++) {
      int wl = wl0 + pr;
      #pragma unroll
      for (int u = 0; u < 4; u++) {
        int xo = wl * 8 + u * 2 + hb;
        s_out[cl * 130 + xo] = acc[pr][u];
      }
    }
    BARRIER_LDS();
    // coalesced store: 32 channel-rows x 128 x at fixed yout
    float* obase = out + ((size_t)(cbase + cc * 32) * 128 + yout) * 128;
    #pragma unroll
    for (int it = 0; it < 4; it++) {
      int q2 = t + it * 256;
      int rowc = q2 >> 5;       // 0..31 (channel within chunk)
      int col4 = q2 & 31;       // float4 index within row
      const float* sp = s_out + rowc * 130 + col4 * 4;
      float4 v = make_float4(sp[0], sp[1], sp[2], sp[3]);
      *(float4*)(obase + (size_t)rowc * (128 * 128) + col4 * 4) = v;
    }
  }
}

extern "C" void kernel_launch(void* const* d_in, const int* in_sizes, int n_in,
                              void* d_out, int out_size, void* d_ws, size_t ws_size,
                              hipStream_t stream) {
  const float* x      = (const float*)d_in[0];
  const float* w_comp = (const float*)d_in[1];
  const float* b_comp = (const float*)d_in[2];
  const float* w_ker  = (const float*)d_in[3];
  const float* b_ker  = (const float*)d_in[4];
  const float* w_off  = (const float*)d_in[5];
  const float* b_off  = (const float*)d_in[6];
  float* out = (float*)d_out;
  float* ws = (float*)d_ws;
  float* offb  = ws + WS_OFF;
  float* maskb = ws + WS_MASK;
  float* wT    = ws + WS_WT;
  float* wcT   = ws + WS_CX;   // cx region is dead post-fusion; wcT lives there

  hipLaunchKernelGGL(k_wt, dim3((NWT + NWC + 255) / 256), dim3(256), 0, stream,
                     w_ker, w_off, w_comp, wT, wcT);
  hipLaunchKernelGGL(k_cs, dim3(64, 4), dim3(1024), 0, stream,
                     x, wcT, b_comp, wT, b_ker, b_off, offb, maskb);
  hipLaunchKernelGGL(k_carafe, dim3(1024), dim3(256), 0, stream, x, offb, maskb, out);
}